// Round 4
// baseline (7646.899 us; speedup 1.0000x reference)
//
#include <hip/hip_runtime.h>
#include <hip/hip_bf16.h>
#include <math.h>

#define LSEQ 4096
#define EMBD 512
#define HIDD 512      // per-direction hidden
#define G4   2048     // 4*HIDD
#define NTAGS 8
#define START_TAG 6
#define STOP_TAG 7
#define NEGV (-10000.0f)
#define PWG 128       // workgroups per direction (one per CU)
#define HUW 4         // hidden units per WG = waves per WG
#define HTAG 2.0f     // readiness tag bias: stored h+2 in (1,3); poison/zero < 0.5

__device__ __forceinline__ float sigmf(float x) {
    return 1.0f / (1.0f + __expf(-x));
}
__device__ __forceinline__ float tanhfast(float x) {
    float ax = fabsf(x);
    float e = __expf(-2.0f * ax);
    float r = (1.0f - e) / (1.0f + e);
    return copysignf(r, x);
}

// ---------------------------------------------------------------------------
// Kernel 1: fused embedding gather + x-projection GEMM (both directions)
// ---------------------------------------------------------------------------
__global__ __launch_bounds__(256) void gemm_xproj_kernel(
    const int* __restrict__ sent,
    const float* __restrict__ wembed,
    const float* __restrict__ wih_f, const float* __restrict__ b_f,
    const float* __restrict__ wih_b, const float* __restrict__ b_b,
    float* __restrict__ xpf, float* __restrict__ xpb)
{
    const int dir = blockIdx.z;
    const float* __restrict__ wih  = dir ? wih_b : wih_f;
    const float* __restrict__ bias = dir ? b_b   : b_f;
    float* __restrict__ out        = dir ? xpb   : xpf;
    const int bm = blockIdx.y * 128;
    const int bn = blockIdx.x * 128;
    const int tid = threadIdx.x;
    const int ty = tid >> 4, tx = tid & 15;

    __shared__ float As[16][128];
    __shared__ float Bs[16][128];
    __shared__ int sid[128];

    if (tid < 128) sid[tid] = sent[bm + tid];
    __syncthreads();

    float acc[8][8];
#pragma unroll
    for (int i = 0; i < 8; ++i)
#pragma unroll
        for (int j = 0; j < 8; ++j) acc[i][j] = 0.f;

    for (int k0 = 0; k0 < EMBD; k0 += 16) {
#pragma unroll
        for (int it = 0; it < 2; ++it) {
            int idx = it * 256 + tid;
            int r = idx >> 2, k4 = idx & 3;
            float4 av = *(const float4*)(wembed + (size_t)sid[r] * EMBD + k0 + k4 * 4);
            As[k4 * 4 + 0][r] = av.x; As[k4 * 4 + 1][r] = av.y;
            As[k4 * 4 + 2][r] = av.z; As[k4 * 4 + 3][r] = av.w;
            float4 bv = *(const float4*)(wih + (size_t)(bn + r) * EMBD + k0 + k4 * 4);
            Bs[k4 * 4 + 0][r] = bv.x; Bs[k4 * 4 + 1][r] = bv.y;
            Bs[k4 * 4 + 2][r] = bv.z; Bs[k4 * 4 + 3][r] = bv.w;
        }
        __syncthreads();
#pragma unroll
        for (int k = 0; k < 16; ++k) {
            float4 a0 = *(const float4*)&As[k][ty * 8];
            float4 a1 = *(const float4*)&As[k][ty * 8 + 4];
            float4 b0 = *(const float4*)&Bs[k][tx * 8];
            float4 b1 = *(const float4*)&Bs[k][tx * 8 + 4];
            float a[8] = {a0.x, a0.y, a0.z, a0.w, a1.x, a1.y, a1.z, a1.w};
            float b[8] = {b0.x, b0.y, b0.z, b0.w, b1.x, b1.y, b1.z, b1.w};
#pragma unroll
            for (int i = 0; i < 8; ++i)
#pragma unroll
                for (int j = 0; j < 8; ++j)
                    acc[i][j] = fmaf(a[i], b[j], acc[i][j]);
        }
        __syncthreads();
    }

    float bj[8];
#pragma unroll
    for (int j = 0; j < 8; ++j) bj[j] = bias[bn + tx * 8 + j];
#pragma unroll
    for (int i = 0; i < 8; ++i) {
        int m = bm + ty * 8 + i;
        float* orow = out + (size_t)m * G4 + bn + tx * 8;
        float4 s0 = make_float4(acc[i][0] + bj[0], acc[i][1] + bj[1],
                                acc[i][2] + bj[2], acc[i][3] + bj[3]);
        float4 s1 = make_float4(acc[i][4] + bj[4], acc[i][5] + bj[5],
                                acc[i][6] + bj[6], acc[i][7] + bj[7]);
        *(float4*)(orow) = s0;
        *(float4*)(orow + 4) = s1;
    }
}

// ---------------------------------------------------------------------------
// Kernel 2: wave-per-hidden-unit persistent LSTM. 256 WGs (128/dir), 256
// threads = 4 waves each. Wave w owns hidden unit Hidx = wg*4+w with ALL
// FOUR gates in-wave: lane = gate(2b) x colslice(4b); 32 resident weights
// per lane (asm-pinned so the allocator cannot sink them — r2/r3 lesson).
// Per step: each thread polls 2 tagged h words (both loads in flight),
// publishes to double-buffered padded LDS, ONE __syncthreads, 8x
// ds_read_b128 (2-way aliasing = free), 32 FMAs, 4-shuffle reduce within
// the 16-lane gate group, 3 shuffles to gather i/f/g/o, redundant gate math
// in all lanes, lane 0 stores h+HTAG. No cross-wave totals, no second
// barrier, no fences/counters (data-embedded readiness, validated r1-r3).
// ---------------------------------------------------------------------------
__global__ __launch_bounds__(256) void lstm_kernel(
    const float* __restrict__ xpf, const float* __restrict__ xpb,
    const float* __restrict__ whh_f, const float* __restrict__ whh_b,
    float* __restrict__ hf, float* __restrict__ hb)
{
    const int bid = blockIdx.x;
    const int dir = bid >> 7;
    const int wg  = bid & 127;
    const float* __restrict__ xp  = dir ? xpb : xpf;
    const float* __restrict__ whh = dir ? whh_b : whh_f;
    float* __restrict__ hout      = dir ? hb : hf;

    const int t0 = threadIdx.x;
    const int w  = t0 >> 6;        // wave id == local hidden unit
    const int l  = t0 & 63;
    const int g  = l >> 4;         // gate (i,f,g,o)
    const int q  = l & 15;         // 32-col slice index
    const int Hidx = wg * HUW + w;
    const int grow = g * HIDD + Hidx;

    // 32 resident weights per lane, pinned so they cannot be re-loaded in-loop
    float4 wv[8];
    {
        const float4* wr = (const float4*)(whh + (size_t)grow * HIDD) + q * 8;
#pragma unroll
        for (int j = 0; j < 8; ++j) wv[j] = wr[j];
#pragma unroll
        for (int j = 0; j < 8; ++j)
            asm volatile("" : "+v"(wv[j].x), "+v"(wv[j].y),
                              "+v"(wv[j].z), "+v"(wv[j].w));
    }
    // analytic removal of the +2 tag bias
    float twoSumW = 0.f;
#pragma unroll
    for (int j = 0; j < 8; ++j)
        twoSumW += (wv[j].x + wv[j].y) + (wv[j].z + wv[j].w);
    twoSumW *= 2.0f;

    // double-buffered h: 16 slices of 32 floats padded to 36 (144B: 16B-aligned,
    // ds_read_b128 lands 2 lanes per 4-bank group = free 2-way)
    __shared__ float hs[2][16 * 36];
    hs[0][((t0      ) >> 5) * 36 + ((t0      ) & 31)] = HTAG;
    hs[0][((t0 + 256) >> 5) * 36 + ((t0 + 256) & 31)] = HTAG;

    float c = 0.f;
    float xg = 0.f;
    if (q == 0) xg = xp[(size_t)(dir ? (LSEQ - 1) : 0) * G4 + grow];

    for (int t = 0; t < LSEQ; ++t) {
        const int row = dir ? (LSEQ - 1 - t) : t;
        float xg_n = 0.f;
        if (q == 0 && t + 1 < LSEQ) {   // prefetch next x-gate, overlaps poll
            const int nrow = dir ? (LSEQ - 2 - t) : (t + 1);
            xg_n = xp[(size_t)nrow * G4 + grow];
        }

        float* hcur = hs[t & 1];
        if (t > 0) {
            const int prow = dir ? (LSEQ - t) : (t - 1);
            const float* s0 = hout + (size_t)prow * HIDD + t0;
            const float* s1 = s0 + 256;
            // both loads in flight before either wait
            float v0 = __hip_atomic_load(s0, __ATOMIC_RELAXED,
                                         __HIP_MEMORY_SCOPE_AGENT);
            float v1 = __hip_atomic_load(s1, __ATOMIC_RELAXED,
                                         __HIP_MEMORY_SCOPE_AGENT);
            while (!(v0 > 0.5f))
                v0 = __hip_atomic_load(s0, __ATOMIC_RELAXED,
                                       __HIP_MEMORY_SCOPE_AGENT);
            while (!(v1 > 0.5f))
                v1 = __hip_atomic_load(s1, __ATOMIC_RELAXED,
                                       __HIP_MEMORY_SCOPE_AGENT);
            hcur[((t0      ) >> 5) * 36 + ((t0      ) & 31)] = v0;
            hcur[((t0 + 256) >> 5) * 36 + ((t0 + 256) & 31)] = v1;
        }
        __syncthreads();   // the ONLY barrier per step (dbuf handles WAR)

        const float4* h4 = (const float4*)(hcur + q * 36);
        float4 h0 = h4[0], h1 = h4[1], h2 = h4[2], h3 = h4[3];
        float4 h4v = h4[4], h5 = h4[5], h6 = h4[6], h7 = h4[7];
        float a0 = 0.f, a1 = 0.f, a2 = 0.f, a3 = 0.f;
        a0 = fmaf(wv[0].x, h0.x, a0); a0 = fmaf(wv[0].y, h0.y, a0);
        a0 = fmaf(wv[0].z, h0.z, a0); a0 = fmaf(wv[0].w, h0.w, a0);
        a1 = fmaf(wv[1].x, h1.x, a1); a1 = fmaf(wv[1].y, h1.y, a1);
        a1 = fmaf(wv[1].z, h1.z, a1); a1 = fmaf(wv[1].w, h1.w, a1);
        a2 = fmaf(wv[2].x, h2.x, a2); a2 = fmaf(wv[2].y, h2.y, a2);
        a2 = fmaf(wv[2].z, h2.z, a2); a2 = fmaf(wv[2].w, h2.w, a2);
        a3 = fmaf(wv[3].x, h3.x, a3); a3 = fmaf(wv[3].y, h3.y, a3);
        a3 = fmaf(wv[3].z, h3.z, a3); a3 = fmaf(wv[3].w, h3.w, a3);
        a0 = fmaf(wv[4].x, h4v.x, a0); a0 = fmaf(wv[4].y, h4v.y, a0);
        a0 = fmaf(wv[4].z, h4v.z, a0); a0 = fmaf(wv[4].w, h4v.w, a0);
        a1 = fmaf(wv[5].x, h5.x, a1); a1 = fmaf(wv[5].y, h5.y, a1);
        a1 = fmaf(wv[5].z, h5.z, a1); a1 = fmaf(wv[5].w, h5.w, a1);
        a2 = fmaf(wv[6].x, h6.x, a2); a2 = fmaf(wv[6].y, h6.y, a2);
        a2 = fmaf(wv[6].z, h6.z, a2); a2 = fmaf(wv[6].w, h6.w, a2);
        a3 = fmaf(wv[7].x, h7.x, a3); a3 = fmaf(wv[7].y, h7.y, a3);
        a3 = fmaf(wv[7].z, h7.z, a3); a3 = fmaf(wv[7].w, h7.w, a3);
        float tot = ((a0 + a1) + (a2 + a3)) - twoSumW;

        // reduce across the 16-lane gate group
        tot += __shfl_xor(tot, 1);
        tot += __shfl_xor(tot, 2);
        tot += __shfl_xor(tot, 4);
        tot += __shfl_xor(tot, 8);
        if (q == 0) tot += xg;

        // gather the 4 gate totals (lanes 0,16,32,48), redundant in all lanes
        float ti = __shfl(tot, 0);
        float tf = __shfl(tot, 16);
        float tg = __shfl(tot, 32);
        float to = __shfl(tot, 48);
        c = fmaf(sigmf(tf), c, sigmf(ti) * tanhfast(tg));
        float h = sigmf(to) * tanhfast(c);

        if (l == 0)
            __hip_atomic_store(&hout[(size_t)row * HIDD + Hidx], h + HTAG,
                               __ATOMIC_RELAXED, __HIP_MEMORY_SCOPE_AGENT);
        xg = xg_n;
    }
}

// ---------------------------------------------------------------------------
// Kernel 3: feats = [hf|hb] @ w_tag.T + b_tag. One wave per sequence row.
// hf/hb hold tagged values (h+2): subtract on load.
// ---------------------------------------------------------------------------
__global__ __launch_bounds__(256) void feats_kernel(
    const float* __restrict__ hf, const float* __restrict__ hb,
    const float* __restrict__ wtag, const float* __restrict__ btag,
    float* __restrict__ feats)
{
    const int wave = threadIdx.x >> 6;
    const int lane = threadIdx.x & 63;
    const int row = blockIdx.x * 4 + wave;
    const float4* a4 = (const float4*)(hf + (size_t)row * HIDD);
    const float4* b4 = (const float4*)(hb + (size_t)row * HIDD);
    float4 a0 = a4[lane * 2], a1 = a4[lane * 2 + 1];
    float4 b0 = b4[lane * 2], b1 = b4[lane * 2 + 1];
    a0.x -= HTAG; a0.y -= HTAG; a0.z -= HTAG; a0.w -= HTAG;
    a1.x -= HTAG; a1.y -= HTAG; a1.z -= HTAG; a1.w -= HTAG;
    b0.x -= HTAG; b0.y -= HTAG; b0.z -= HTAG; b0.w -= HTAG;
    b1.x -= HTAG; b1.y -= HTAG; b1.z -= HTAG; b1.w -= HTAG;
    float acc[NTAGS];
#pragma unroll
    for (int n = 0; n < NTAGS; ++n) {
        const float4* wf = (const float4*)(wtag + (size_t)n * 1024);
        const float4* wb = (const float4*)(wtag + (size_t)n * 1024 + HIDD);
        float4 w0 = wf[lane * 2], w1 = wf[lane * 2 + 1];
        float4 v0 = wb[lane * 2], v1 = wb[lane * 2 + 1];
        acc[n] = a0.x * w0.x + a0.y * w0.y + a0.z * w0.z + a0.w * w0.w
               + a1.x * w1.x + a1.y * w1.y + a1.z * w1.z + a1.w * w1.w
               + b0.x * v0.x + b0.y * v0.y + b0.z * v0.z + b0.w * v0.w
               + b1.x * v1.x + b1.y * v1.y + b1.z * v1.z + b1.w * v1.w;
    }
#pragma unroll
    for (int d = 1; d < 64; d <<= 1)
#pragma unroll
        for (int n = 0; n < NTAGS; ++n)
            acc[n] += __shfl_xor(acc[n], d);
    if (lane == 0) {
#pragma unroll
        for (int n = 0; n < NTAGS; ++n)
            feats[(size_t)row * NTAGS + n] = acc[n] + btag[n];
    }
}

// ---------------------------------------------------------------------------
// Kernel 4: Viterbi forward + backtrack. One block; wave 0 does the scan,
// all 256 threads cooperatively stage feats chunks into LDS.
// ---------------------------------------------------------------------------
__global__ __launch_bounds__(256) void viterbi_kernel(
    const float* __restrict__ feats, const float* __restrict__ trans,
    float* __restrict__ out)
{
    __shared__ float flds[512 * NTAGS];       // 16 KB chunk of feats
    __shared__ unsigned int bp[LSEQ];         // 16 KB packed backptrs
    const int tid = threadIdx.x;
    const int l = tid & 63;
    const int n = (l >> 3) & 7;               // next tag
    const int p = l & 7;                      // prev tag
    float tr = 0.f, trstop = 0.f;
    if (tid < 64) {
        tr = trans[n * NTAGS + p];
        trstop = trans[STOP_TAG * NTAGS + p];
    }
    float fvp = (p == START_TAG) ? 0.f : NEGV;   // fv[p], replicated per n-group

    for (int tc = 0; tc < LSEQ; tc += 512) {
        __syncthreads();
        for (int i = tid; i < 1024; i += 256)
            ((float4*)flds)[i] = ((const float4*)(feats + (size_t)tc * NTAGS))[i];
        __syncthreads();
        if (tid < 64) {
            for (int tt = 0; tt < 512; ++tt) {
                float s = fvp + tr;
                float v = s; int bi = p;
#pragma unroll
                for (int d = 1; d <= 4; d <<= 1) {
                    float ovv = __shfl_xor(v, d);
                    int oii = __shfl_xor(bi, d);
                    if (ovv > v || (ovv == v && oii < bi)) { v = ovv; bi = oii; }
                }
                float fvn = v + flds[tt * NTAGS + n];
                unsigned wbits = 0;
#pragma unroll
                for (int k = 0; k < 8; ++k)
                    wbits |= (unsigned)(__shfl(bi, k * 8) & 7) << (k * 4);
                if (l == 0) bp[tc + tt] = wbits;
                fvp = __shfl(fvn, p * 8);
            }
        }
    }

    if (tid < 64) {
        float tv = fvp + trstop;
        float v = tv; int bi = p;
#pragma unroll
        for (int d = 1; d <= 4; d <<= 1) {
            float ovv = __shfl_xor(v, d);
            int oii = __shfl_xor(bi, d);
            if (ovv > v || (ovv == v && oii < bi)) { v = ovv; bi = oii; }
        }
        if (tid == 0) {
            out[0] = v;                      // path_score
            int tag = bi;
            out[LSEQ] = (float)tag;          // path[L-1]
            for (int t = LSEQ - 1; t >= 1; --t) {
                tag = (int)((bp[t] >> (tag * 4)) & 7u);
                out[t] = (float)tag;         // path[t-1] at out[1 + (t-1)]
            }
        }
    }
}

// ---------------------------------------------------------------------------
extern "C" void kernel_launch(void* const* d_in, const int* in_sizes, int n_in,
                              void* d_out, int out_size, void* d_ws, size_t ws_size,
                              hipStream_t stream)
{
    (void)in_sizes; (void)n_in; (void)out_size; (void)ws_size;
    const int*   sent   = (const int*)d_in[0];
    const float* wembed = (const float*)d_in[1];
    const float* wih_f  = (const float*)d_in[2];
    const float* whh_f  = (const float*)d_in[3];
    const float* b_f    = (const float*)d_in[4];
    const float* wih_b  = (const float*)d_in[5];
    const float* whh_b  = (const float*)d_in[6];
    const float* b_b    = (const float*)d_in[7];
    const float* wtag   = (const float*)d_in[8];
    const float* btag   = (const float*)d_in[9];
    const float* trans  = (const float*)d_in[10];
    float* out = (float*)d_out;

    float* ws = (float*)d_ws;
    float* xpf   = ws;
    float* xpb   = xpf + (size_t)LSEQ * G4;
    float* hf    = xpb + (size_t)LSEQ * G4;
    float* hb    = hf  + (size_t)LSEQ * HIDD;
    float* feats = hb  + (size_t)LSEQ * HIDD;

    dim3 g1(G4 / 128, LSEQ / 128, 2);
    gemm_xproj_kernel<<<g1, 256, 0, stream>>>(sent, wembed, wih_f, b_f,
                                              wih_b, b_b, xpf, xpb);
    lstm_kernel<<<dim3(2 * PWG), 256, 0, stream>>>(xpf, xpb, whh_f, whh_b,
                                                   hf, hb);
    feats_kernel<<<dim3(LSEQ / 4), 256, 0, stream>>>(hf, hb, wtag, btag, feats);
    viterbi_kernel<<<dim3(1), 256, 0, stream>>>(feats, trans, out);
}